// Round 1
// baseline (1058.494 us; speedup 1.0000x reference)
//
#include <hip/hip_runtime.h>
#include <hip/hip_bf16.h>

typedef __attribute__((ext_vector_type(8))) short short8;
typedef __attribute__((ext_vector_type(4))) float floatx4;

using bf16 = __hip_bfloat16;

__device__ __forceinline__ void cp16_g2l(bf16* lds, const bf16* g) {
  __builtin_amdgcn_global_load_lds(
      (const __attribute__((address_space(1))) unsigned int*)g,
      (__attribute__((address_space(3))) unsigned int*)lds,
      16, 0, 0);
}

__device__ __forceinline__ float gelu_exact(float x) {
  return 0.5f * x * (1.0f + erff(x * 0.70710678118654752f));
}

// C[M,N] = A[M,K] @ Bt[N,K]^T  (both bf16, fp32 accum), batched via blockIdx.z.
// MODE 0: out bf16 = acc + bias
// MODE 1: out f32  = acc * scale
// MODE 2: out bf16 = acc
// MODE 3: out f32  = acc + bias + resid   (resid may alias out)
// MODE 4: out bf16 = gelu(acc + bias)
template<int MODE>
__global__ __launch_bounds__(256)
void gemm_bt(const bf16* __restrict__ A, long sAb,
             const bf16* __restrict__ Bt, long sBb,
             const float* __restrict__ bias,
             const float* __restrict__ resid,
             void* __restrict__ out, long sOb,
             int N, int K, float scale)
{
  __shared__ bf16 sA[2][128 * 32];
  __shared__ bf16 sB[2][128 * 32];

  const int tid = threadIdx.x;
  const int l = tid & 63, w = tid >> 6;
  const int bz = blockIdx.z;
  const long row0 = (long)blockIdx.x * 128;
  const long col0 = (long)blockIdx.y * 128;

  const bf16* Ab = A + (long)bz * sAb;
  const bf16* Bb = Bt + (long)bz * sBb;

  // staging: each wave covers 16 rows (16 rows * 64B = 64 lanes * 16B)
  const int sr = (w << 4) + (l >> 2);   // 0..63
  const int kc = (l & 3) << 3;          // k element offset 0,8,16,24
  const bf16* gA = Ab + (row0 + sr) * (long)K + kc;
  const bf16* gB = Bb + (col0 + sr) * (long)K + kc;
  bf16* lA = &sA[0][sr * 32 + kc];
  bf16* lB = &sB[0][sr * 32 + kc];
  const long skip = 64 * (long)K;

  floatx4 acc[4][4];
  #pragma unroll
  for (int i = 0; i < 4; ++i)
    #pragma unroll
    for (int j = 0; j < 4; ++j)
      acc[i][j] = (floatx4){0.f, 0.f, 0.f, 0.f};

  const int wr = (w >> 1) & 1, wc = w & 1;
  const int g = l >> 4, t = l & 15;
  const int aoff = (wr * 64 + t) * 32 + g * 8;
  const int boff = (wc * 64 + t) * 32 + g * 8;

  const int nt = K >> 5;

  // prologue: stage tile 0 into buf 0
  cp16_g2l(lA,           gA);
  cp16_g2l(lA + 64 * 32, gA + skip);
  cp16_g2l(lB,           gB);
  cp16_g2l(lB + 64 * 32, gB + skip);
  __syncthreads();   // drains vmcnt(0)

  for (int kt = 0; kt < nt; ++kt) {
    const int cur = kt & 1;
    if (kt + 1 < nt) {
      const long ko = (long)(kt + 1) << 5;
      bf16* dA = lA + (cur ^ 1) * (128 * 32);
      bf16* dB = lB + (cur ^ 1) * (128 * 32);
      cp16_g2l(dA,           gA + ko);
      cp16_g2l(dA + 64 * 32, gA + ko + skip);
      cp16_g2l(dB,           gB + ko);
      cp16_g2l(dB + 64 * 32, gB + ko + skip);
    }
    const bf16* cA = &sA[cur][0];
    const bf16* cB = &sB[cur][0];
    short8 a[4], b[4];
    #pragma unroll
    for (int m = 0; m < 4; ++m) a[m] = *(const short8*)(cA + aoff + m * 512);
    #pragma unroll
    for (int n = 0; n < 4; ++n) b[n] = *(const short8*)(cB + boff + n * 512);
    #pragma unroll
    for (int m = 0; m < 4; ++m)
      #pragma unroll
      for (int n = 0; n < 4; ++n)
        acc[m][n] = __builtin_amdgcn_mfma_f32_16x16x32_bf16(a[m], b[n], acc[m][n], 0, 0, 0);
    __syncthreads();   // drains this iter's prefetch + everyone's ds_reads
  }

  // epilogue: C/D layout col = lane&15, row = (lane>>4)*4 + r  [m89]
  const long orow = row0 + wr * 64 + (g << 2);
  const long ocol = col0 + wc * 64 + t;

  if constexpr (MODE == 0 || MODE == 2 || MODE == 4) {
    bf16* O = (bf16*)out + (long)bz * sOb;
    #pragma unroll
    for (int n = 0; n < 4; ++n) {
      const long cc = ocol + n * 16;
      float bv = 0.f;
      if constexpr (MODE != 2) bv = bias[cc];
      #pragma unroll
      for (int m = 0; m < 4; ++m) {
        #pragma unroll
        for (int r = 0; r < 4; ++r) {
          float vv = acc[m][n][r] + bv;
          if constexpr (MODE == 4) vv = gelu_exact(vv);
          O[(orow + m * 16 + r) * (long)N + cc] = __float2bfloat16(vv);
        }
      }
    }
  } else if constexpr (MODE == 1) {
    float* O = (float*)out + (long)bz * sOb;
    #pragma unroll
    for (int n = 0; n < 4; ++n) {
      const long cc = ocol + n * 16;
      #pragma unroll
      for (int m = 0; m < 4; ++m)
        #pragma unroll
        for (int r = 0; r < 4; ++r)
          O[(orow + m * 16 + r) * (long)N + cc] = acc[m][n][r] * scale;
    }
  } else {  // MODE 3
    float* O = (float*)out;
    #pragma unroll
    for (int n = 0; n < 4; ++n) {
      const long cc = ocol + n * 16;
      const float bv = bias[cc];
      #pragma unroll
      for (int m = 0; m < 4; ++m) {
        #pragma unroll
        for (int r = 0; r < 4; ++r) {
          const long idx = (orow + m * 16 + r) * (long)N + cc;
          O[idx] = acc[m][n][r] + bv + resid[idx];
        }
      }
    }
  }
}

// row LayerNorm over D=768, fp32 in -> bf16 out
__global__ __launch_bounds__(256)
void ln_kernel(const float* __restrict__ X, const float* __restrict__ G,
               const float* __restrict__ Bv, bf16* __restrict__ H)
{
  const int tid = threadIdx.x;
  const long row = blockIdx.x;
  const float* xr = X + row * 768;
  const float v0 = xr[tid], v1 = xr[tid + 256], v2 = xr[tid + 512];
  float s = v0 + v1 + v2;
  float s2 = v0 * v0 + v1 * v1 + v2 * v2;
  #pragma unroll
  for (int o = 32; o > 0; o >>= 1) {
    s += __shfl_xor(s, o);
    s2 += __shfl_xor(s2, o);
  }
  __shared__ float red[8];
  const int w = tid >> 6, l = tid & 63;
  if (l == 0) { red[w] = s; red[w + 4] = s2; }
  __syncthreads();
  s = red[0] + red[1] + red[2] + red[3];
  s2 = red[4] + red[5] + red[6] + red[7];
  const float mu = s * (1.f / 768.f);
  const float var = s2 * (1.f / 768.f) - mu * mu;
  const float rstd = rsqrtf(var + 1e-5f);
  bf16* hr = H + row * 768;
  hr[tid]       = __float2bfloat16((v0 - mu) * rstd * G[tid]       + Bv[tid]);
  hr[tid + 256] = __float2bfloat16((v1 - mu) * rstd * G[tid + 256] + Bv[tid + 256]);
  hr[tid + 512] = __float2bfloat16((v2 - mu) * rstd * G[tid + 512] + Bv[tid + 512]);
}

// row softmax over 2048 keys, fp32 scores -> bf16 probs
__global__ __launch_bounds__(256)
void softmax_kernel(const float* __restrict__ S, bf16* __restrict__ P)
{
  const int tid = threadIdx.x;
  const long row = blockIdx.x;
  const float* sr = S + row * 2048;
  float v[8];
  float mx = -1e30f;
  #pragma unroll
  for (int j = 0; j < 8; ++j) { v[j] = sr[tid + 256 * j]; mx = fmaxf(mx, v[j]); }
  #pragma unroll
  for (int o = 32; o > 0; o >>= 1) mx = fmaxf(mx, __shfl_xor(mx, o));
  __shared__ float red[4];
  const int w = tid >> 6, l = tid & 63;
  if (l == 0) red[w] = mx;
  __syncthreads();
  mx = fmaxf(fmaxf(red[0], red[1]), fmaxf(red[2], red[3]));
  float sum = 0.f;
  #pragma unroll
  for (int j = 0; j < 8; ++j) { v[j] = __expf(v[j] - mx); sum += v[j]; }
  #pragma unroll
  for (int o = 32; o > 0; o >>= 1) sum += __shfl_xor(sum, o);
  __syncthreads();
  if (l == 0) red[w] = sum;
  __syncthreads();
  sum = red[0] + red[1] + red[2] + red[3];
  const float inv = 1.f / sum;
  bf16* pr = P + row * 2048;
  #pragma unroll
  for (int j = 0; j < 8; ++j) pr[tid + 256 * j] = __float2bfloat16(v[j] * inv);
}

// Wt[n][k] = bf16(W[k][n]) ; W fp32 [K][N]. block (32,8)
__global__ void transpose_w(const float* __restrict__ W, bf16* __restrict__ Wt,
                            int K, int N)
{
  __shared__ float tile[32][33];
  const int n0 = blockIdx.x * 32, k0 = blockIdx.y * 32;
  const int tx = threadIdx.x, ty = threadIdx.y;
  #pragma unroll
  for (int j = ty; j < 32; j += 8)
    tile[j][tx] = W[(long)(k0 + j) * N + n0 + tx];
  __syncthreads();
  #pragma unroll
  for (int j = ty; j < 32; j += 8)
    Wt[(long)(n0 + j) * K + k0 + tx] = __float2bfloat16(tile[tx][j]);
}

// Vt[b][d][s] = V[b*2048+s][d]  (bf16). block (32,8), grid (D/32, S/32, B)
__global__ void transpose_v(const bf16* __restrict__ V, bf16* __restrict__ Vt)
{
  __shared__ bf16 tile[32][33];
  const int d0 = blockIdx.x * 32, s0 = blockIdx.y * 32, b = blockIdx.z;
  const int tx = threadIdx.x, ty = threadIdx.y;
  #pragma unroll
  for (int j = ty; j < 32; j += 8)
    tile[j][tx] = V[((long)b * 2048 + s0 + j) * 768 + d0 + tx];
  __syncthreads();
  #pragma unroll
  for (int j = ty; j < 32; j += 8)
    Vt[(long)b * 768 * 2048 + (long)(d0 + j) * 2048 + s0 + tx] = tile[tx][j];
}

extern "C" void kernel_launch(void* const* d_in, const int* in_sizes, int n_in,
                              void* d_out, int out_size, void* d_ws, size_t ws_size,
                              hipStream_t stream)
{
  const float* x     = (const float*)d_in[0];
  const float* ln1g  = (const float*)d_in[1];
  const float* ln1b  = (const float*)d_in[2];
  const float* ln2g  = (const float*)d_in[3];
  const float* ln2b  = (const float*)d_in[4];
  const float* Wq    = (const float*)d_in[5];
  const float* bq    = (const float*)d_in[6];
  const float* Wk    = (const float*)d_in[7];
  const float* bk    = (const float*)d_in[8];
  const float* Wv    = (const float*)d_in[9];
  const float* bvv   = (const float*)d_in[10];
  const float* Wo    = (const float*)d_in[11];
  const float* bo    = (const float*)d_in[12];
  const float* Wfc   = (const float*)d_in[13];
  const float* bfc   = (const float*)d_in[14];
  const float* Wproj = (const float*)d_in[15];
  const float* bproj = (const float*)d_in[16];
  float* out = (float*)d_out;

  constexpr int Bz = 8, S = 2048, D = 768, Hh = 3072;
  constexpr long Mtot = (long)Bz * S;  // 16384

  char* ws = (char*)d_ws;
  size_t off = 0;
  auto alloc = [&](size_t bytes) -> char* {
    char* p = ws + off;
    off += (bytes + 255) & ~(size_t)255;
    return p;
  };
  bf16* wqT  = (bf16*)alloc((size_t)D * D * 2);
  bf16* wkT  = (bf16*)alloc((size_t)D * D * 2);
  bf16* wvT  = (bf16*)alloc((size_t)D * D * 2);
  bf16* woT  = (bf16*)alloc((size_t)D * D * 2);
  bf16* wfcT = (bf16*)alloc((size_t)Hh * D * 2);
  bf16* wprT = (bf16*)alloc((size_t)D * Hh * 2);
  bf16* hb   = (bf16*)alloc((size_t)Mtot * D * 2);
  bf16* qb   = (bf16*)alloc((size_t)Mtot * D * 2);  // later reused as y
  bf16* kb   = (bf16*)alloc((size_t)Mtot * D * 2);
  bf16* vb   = (bf16*)alloc((size_t)Mtot * D * 2);
  bf16* vtb  = (bf16*)alloc((size_t)Mtot * D * 2);

  int nbat = Bz;
  size_t region = (size_t)nbat * S * S * 6;              // scores f32 + attn bf16
  const size_t mbytes = (size_t)Mtot * Hh * 2;           // MLP hidden bf16
  if (region < mbytes) region = mbytes;
  if (off + region > ws_size) {                          // fallback: per-batch attention
    nbat = 1;
    region = mbytes;  // >= 1*S*S*6
  }
  char* reg = alloc(region);
  float* scores = (float*)reg;
  bf16* attn = (bf16*)(reg + (size_t)nbat * S * S * 4);
  bf16* mb = (bf16*)reg;  // aliases scores/attn region (used after attention done)

  const dim3 tb(32, 8);

  // weight prep (bf16, transposed to [N][K])
  transpose_w<<<dim3(D / 32, D / 32), tb, 0, stream>>>(Wq, wqT, D, D);
  transpose_w<<<dim3(D / 32, D / 32), tb, 0, stream>>>(Wk, wkT, D, D);
  transpose_w<<<dim3(D / 32, D / 32), tb, 0, stream>>>(Wv, wvT, D, D);
  transpose_w<<<dim3(D / 32, D / 32), tb, 0, stream>>>(Wo, woT, D, D);
  transpose_w<<<dim3(Hh / 32, D / 32), tb, 0, stream>>>(Wfc, wfcT, D, Hh);
  transpose_w<<<dim3(D / 32, Hh / 32), tb, 0, stream>>>(Wproj, wprT, Hh, D);

  // LN1 -> h (bf16)
  ln_kernel<<<(int)Mtot, 256, 0, stream>>>(x, ln1g, ln1b, hb);

  // QKV projections
  gemm_bt<0><<<dim3(Mtot / 128, D / 128, 1), 256, 0, stream>>>(
      hb, 0, wqT, 0, bq, nullptr, qb, 0, D, D, 1.f);
  gemm_bt<0><<<dim3(Mtot / 128, D / 128, 1), 256, 0, stream>>>(
      hb, 0, wkT, 0, bk, nullptr, kb, 0, D, D, 1.f);
  gemm_bt<0><<<dim3(Mtot / 128, D / 128, 1), 256, 0, stream>>>(
      hb, 0, wvT, 0, bvv, nullptr, vb, 0, D, D, 1.f);
  transpose_v<<<dim3(D / 32, S / 32, Bz), tb, 0, stream>>>(vb, vtb);

  // attention (scores -> softmax -> PV), grouped by nbat batches
  const float sc = 0.03608439182435161f;  // 1/sqrt(768)
  for (int g0 = 0; g0 < Bz; g0 += nbat) {
    const bf16* qg = qb + (long)g0 * S * D;
    const bf16* kg = kb + (long)g0 * S * D;
    const bf16* vtg = vtb + (long)g0 * D * S;
    bf16* yg = qb + (long)g0 * S * D;  // overwrite q rows of this group
    gemm_bt<1><<<dim3(S / 128, S / 128, nbat), 256, 0, stream>>>(
        qg, (long)S * D, kg, (long)S * D, nullptr, nullptr,
        scores, (long)S * S, S, D, sc);
    softmax_kernel<<<nbat * S, 256, 0, stream>>>(scores, attn);
    gemm_bt<2><<<dim3(S / 128, D / 128, nbat), 256, 0, stream>>>(
        attn, (long)S * S, vtg, (long)D * S, nullptr, nullptr,
        yg, (long)S * D, D, S, 1.f);
  }

  // out-projection + residual -> d_out (x1, fp32)
  gemm_bt<3><<<dim3(Mtot / 128, D / 128, 1), 256, 0, stream>>>(
      qb, 0, woT, 0, bo, x, out, 0, D, D, 1.f);

  // LN2 -> h2 (bf16, reuse hb)
  ln_kernel<<<(int)Mtot, 256, 0, stream>>>(out, ln2g, ln2b, hb);

  // MLP: fc + exact GELU -> mb (bf16), then proj + residual (in-place on d_out)
  gemm_bt<4><<<dim3(Mtot / 128, Hh / 128, 1), 256, 0, stream>>>(
      hb, 0, wfcT, 0, bfc, nullptr, mb, 0, Hh, D, 1.f);
  gemm_bt<3><<<dim3(Mtot / 128, D / 128, 1), 256, 0, stream>>>(
      mb, 0, wprT, 0, bproj, out, out, 0, D, Hh, 1.f);
}